// Round 2
// baseline (123.590 us; speedup 1.0000x reference)
//
#include <hip/hip_runtime.h>
#include <hip/hip_bf16.h>
#include <stdint.h>

typedef __bf16 bf16_t;
typedef __bf16 bf16x8 __attribute__((ext_vector_type(8)));
typedef float f32x4 __attribute__((ext_vector_type(4)));

#define NB 2
#define NN 2048
#define ND 1024
#define NH 16
#define DHEAD 64
#define WIN 128

__device__ __forceinline__ void load_lds16(const void* g, void* l) {
  __builtin_amdgcn_global_load_lds(
      (const __attribute__((address_space(1))) uint32_t*)g,
      (__attribute__((address_space(3))) uint32_t*)l, 16, 0, 0);
}

__global__ __launch_bounds__(256) void cast_kernel(const float* __restrict__ in,
                                                   bf16_t* __restrict__ out, int n4) {
  int i = blockIdx.x * 256 + threadIdx.x;
  if (i < n4) {
    float4 v = reinterpret_cast<const float4*>(in)[i];
    union { bf16_t h[4]; uint2 u; } o;
    o.h[0] = (bf16_t)v.x; o.h[1] = (bf16_t)v.y;
    o.h[2] = (bf16_t)v.z; o.h[3] = (bf16_t)v.w;
    reinterpret_cast<uint2*>(out)[i] = o.u;
  }
}

// 4 weight matrices cast in one launch (blockIdx.y selects tensor)
__global__ __launch_bounds__(256) void cast4_kernel(const float* __restrict__ i0, const float* __restrict__ i1,
                                                    const float* __restrict__ i2, const float* __restrict__ i3,
                                                    bf16_t* o0, bf16_t* o1, bf16_t* o2, bf16_t* o3, int n4) {
  int z = blockIdx.y;
  const float* in = (z == 0) ? i0 : (z == 1) ? i1 : (z == 2) ? i2 : i3;
  bf16_t* out = (z == 0) ? o0 : (z == 1) ? o1 : (z == 2) ? o2 : o3;
  int i = blockIdx.x * 256 + threadIdx.x;
  if (i < n4) {
    float4 v = reinterpret_cast<const float4*>(in)[i];
    union { bf16_t h[4]; uint2 u; } o;
    o.h[0] = (bf16_t)v.x; o.h[1] = (bf16_t)v.y;
    o.h[2] = (bf16_t)v.z; o.h[3] = (bf16_t)v.w;
    reinterpret_cast<uint2*>(out)[i] = o.u;
  }
}

// C[m][n] = sum_k A[m][k] * Bw[n][k], K=1024. 128x128 tile, BK=32, 4 waves 2x2.
__device__ __forceinline__ void gemm_tile(const bf16_t* __restrict__ A,
                                          const bf16_t* __restrict__ Bw,
                                          bf16_t* As, bf16_t* Bs,
                                          int m0, int n0, f32x4 acc[4][4]) {
  const int tid  = threadIdx.x;
  const int lane = tid & 63;
  const int wid  = tid >> 6;
  const int wr = wid >> 1, wc = wid & 1;
  const int lrow = lane & 15, lkg = lane >> 4;
  const int srow = lane >> 2, scol = (lane & 3) * 8;

  for (int k0 = 0; k0 < 1024; k0 += 32) {
#pragma unroll
    for (int i = 0; i < 2; ++i) {
      const int rbase = (wid * 2 + i) * 16;
      load_lds16(A  + (size_t)(m0 + rbase + srow) * 1024 + k0 + scol, As + rbase * 32);
      load_lds16(Bw + (size_t)(n0 + rbase + srow) * 1024 + k0 + scol, Bs + rbase * 32);
    }
    __syncthreads();
    bf16x8 af[4], bf[4];
#pragma unroll
    for (int m = 0; m < 4; ++m)
      af[m] = *reinterpret_cast<const bf16x8*>(As + (wr * 64 + m * 16 + lrow) * 32 + lkg * 8);
#pragma unroll
    for (int n = 0; n < 4; ++n)
      bf[n] = *reinterpret_cast<const bf16x8*>(Bs + (wc * 64 + n * 16 + lrow) * 32 + lkg * 8);
#pragma unroll
    for (int m = 0; m < 4; ++m)
#pragma unroll
      for (int n = 0; n < 4; ++n)
        acc[m][n] = __builtin_amdgcn_mfma_f32_16x16x32_bf16(af[m], bf[n], acc[m][n], 0, 0, 0);
    __syncthreads();
  }
}

__global__ __launch_bounds__(256, 2)
void qkv_gemm(const bf16_t* __restrict__ xb,
              const bf16_t* __restrict__ Wqb, const bf16_t* __restrict__ Wkb,
              const bf16_t* __restrict__ Wvb,
              const float* __restrict__ bq, const float* __restrict__ bk,
              const float* __restrict__ bv,
              bf16_t* __restrict__ Qb, bf16_t* __restrict__ Kb,
              bf16_t* __restrict__ VTb) {
  __shared__ __align__(16) bf16_t As[128 * 32];
  __shared__ __align__(16) bf16_t Bs[128 * 32];
  const int z = blockIdx.z;
  const bf16_t* Bw  = (z == 0) ? Wqb : (z == 1) ? Wkb : Wvb;
  const float* bias = (z == 0) ? bq  : (z == 1) ? bk  : bv;
  const int m0 = blockIdx.y * 128, n0 = blockIdx.x * 128;
  f32x4 acc[4][4] = {};
  gemm_tile(xb, Bw, As, Bs, m0, n0, acc);

  const int lane = threadIdx.x & 63;
  const int wid  = threadIdx.x >> 6;
  const int wr = wid >> 1, wc = wid & 1;
  const int lrow = lane & 15, lkg = lane >> 4;
#pragma unroll
  for (int m = 0; m < 4; ++m)
#pragma unroll
    for (int n = 0; n < 4; ++n)
#pragma unroll
      for (int r = 0; r < 4; ++r) {
        int row = m0 + wr * 64 + m * 16 + lkg * 4 + r;   // token
        int col = n0 + wc * 64 + n * 16 + lrow;          // feature
        float val = acc[m][n][r] + bias[col];
        if (z == 2) {
          VTb[((size_t)((row >> 11) * 1024 + col)) * 2048 + (row & 2047)] = (bf16_t)val;
        } else {
          bf16_t* outp = (z == 0) ? Qb : Kb;
          outp[(size_t)row * 1024 + col] = (bf16_t)val;
        }
      }
}

__global__ __launch_bounds__(256, 2)
void out_gemm(const bf16_t* __restrict__ AOb, const bf16_t* __restrict__ Wob,
              const float* __restrict__ bo, float* __restrict__ Cout) {
  __shared__ __align__(16) bf16_t As[128 * 32];
  __shared__ __align__(16) bf16_t Bs[128 * 32];
  const int m0 = blockIdx.y * 128, n0 = blockIdx.x * 128;
  f32x4 acc[4][4] = {};
  gemm_tile(AOb, Wob, As, Bs, m0, n0, acc);

  const int lane = threadIdx.x & 63;
  const int wid  = threadIdx.x >> 6;
  const int wr = wid >> 1, wc = wid & 1;
  const int lrow = lane & 15, lkg = lane >> 4;
#pragma unroll
  for (int m = 0; m < 4; ++m)
#pragma unroll
    for (int n = 0; n < 4; ++n)
#pragma unroll
      for (int r = 0; r < 4; ++r) {
        int row = m0 + wr * 64 + m * 16 + lkg * 4 + r;
        int col = n0 + wc * 64 + n * 16 + lrow;
        Cout[(size_t)row * 1024 + col] = acc[m][n][r] + bo[col];
      }
}

// ---------------------------------------------------------------------------
// Swapped-QK^T flash attention. 4 independent waves/block, 16 q-rows/wave,
// KVBLK=64, zero __syncthreads. Each lane owns q = lane&15: softmax state is
// lane-local scalars; row-reduce = in-reg max/sum + shfl_xor(16),(32).
// ---------------------------------------------------------------------------
__global__ __launch_bounds__(256)
void attn_kernel(const bf16_t* __restrict__ Q, const bf16_t* __restrict__ Kb,
                 const bf16_t* __restrict__ VT, bf16_t* __restrict__ AO) {
  __shared__ uint32_t P_lds[4][16][36];   // per-wave [16 q][32 k halfword-pairs], padded stride

  // XCD-bijective swizzle: 1024 blocks, each XCD gets 128 consecutive work ids
  // -> 4 full (b,h) K/V sets (2MB) per XCD L2.
  const int work = ((blockIdx.x & 7) << 7) | (blockIdx.x >> 3);
  const int qt = work & 31, h = (work >> 5) & 15, b = work >> 9;
  const int tid = threadIdx.x, lane = tid & 63, w = tid >> 6;
  const int lrow = lane & 15, lkg = lane >> 4;
  const int q0 = qt * 64;
  const int qb = q0 + w * 16;
  const int qrow = qb + lrow;

  const bf16_t* qptr = Q + (size_t)(b * NN + qrow) * ND + h * DHEAD + lkg * 8;
  bf16x8 qf0 = *reinterpret_cast<const bf16x8*>(qptr);
  bf16x8 qf1 = *reinterpret_cast<const bf16x8*>(qptr + 32);

  float m_run = -1e30f, l_run = 0.f;
  f32x4 o[4] = {};

  const int kstart = (q0 - WIN > 0) ? (q0 - WIN) : 0;
  const int kend = (q0 + 64 + WIN < NN) ? (q0 + 64 + WIN) : NN;   // always multiple of 64
  const float scale = 0.125f;
  const bf16_t* kb0 = Kb + (size_t)b * NN * ND + h * DHEAD + lkg * 8;
  const bf16_t* vbase = VT + (size_t)((b * NH + h) * DHEAD) * NN;

  for (int kc = kstart; kc < kend; kc += 64) {
    // ---- QK^T (swapped): s[t][r] = S[k = kc+16t+4lkg+r][q = lane&15]
    f32x4 s[4];
#pragma unroll
    for (int t = 0; t < 4; ++t) {
      const bf16_t* kp = kb0 + (size_t)(kc + t * 16 + lrow) * ND;
      bf16x8 kf0 = *reinterpret_cast<const bf16x8*>(kp);
      bf16x8 kf1 = *reinterpret_cast<const bf16x8*>(kp + 32);
      f32x4 zz = {};
      zz = __builtin_amdgcn_mfma_f32_16x16x32_bf16(kf0, qf0, zz, 0, 0, 0);
      zz = __builtin_amdgcn_mfma_f32_16x16x32_bf16(kf1, qf1, zz, 0, 0, 0);
      s[t] = zz;
    }

    // ---- issue V loads early (latency hides under softmax VALU)
    bf16x8 vf0[4], vf1[4];
#pragma unroll
    for (int f = 0; f < 4; ++f) {
      const bf16_t* vp = vbase + (size_t)(f * 16 + lrow) * NN + kc + lkg * 8;
      vf0[f] = *reinterpret_cast<const bf16x8*>(vp);
      vf1[f] = *reinterpret_cast<const bf16x8*>(vp + 32);
    }

    // ---- softmax (lane-local row)
    const bool needs_mask = (kc < qb - 113) || (kc > qb + 65);  // wave-uniform
    float v[4][4];
    float mloc = -1e30f;
    float p[4][4];
    float rsum = 0.f;
    if (needs_mask) {
#pragma unroll
      for (int t = 0; t < 4; ++t)
#pragma unroll
        for (int r = 0; r < 4; ++r) {
          int k = kc + t * 16 + lkg * 4 + r;
          int d = qrow - k;
          bool ok = (unsigned)(d + WIN) <= 2u * WIN;
          v[t][r] = ok ? s[t][r] * scale : -1e30f;
          mloc = fmaxf(mloc, v[t][r]);
        }
      mloc = fmaxf(mloc, __shfl_xor(mloc, 16, 64));
      mloc = fmaxf(mloc, __shfl_xor(mloc, 32, 64));
      float mn = fmaxf(m_run, mloc);
      float corr = __expf(m_run - mn);
      m_run = mn;
#pragma unroll
      for (int t = 0; t < 4; ++t)
#pragma unroll
        for (int r = 0; r < 4; ++r) {
          int k = kc + t * 16 + lkg * 4 + r;
          int d = qrow - k;
          bool ok = (unsigned)(d + WIN) <= 2u * WIN;
          p[t][r] = ok ? __expf(v[t][r] - mn) : 0.f;   // explicit zero: all-masked row safe
          rsum += p[t][r];
        }
      rsum += __shfl_xor(rsum, 16, 64);
      rsum += __shfl_xor(rsum, 32, 64);
      l_run = l_run * corr + rsum;
#pragma unroll
      for (int f = 0; f < 4; ++f) o[f] *= corr;
    } else {
#pragma unroll
      for (int t = 0; t < 4; ++t)
#pragma unroll
        for (int r = 0; r < 4; ++r) {
          v[t][r] = s[t][r] * scale;
          mloc = fmaxf(mloc, v[t][r]);
        }
      mloc = fmaxf(mloc, __shfl_xor(mloc, 16, 64));
      mloc = fmaxf(mloc, __shfl_xor(mloc, 32, 64));
      float mn = fmaxf(m_run, mloc);
      float corr = __expf(m_run - mn);
      m_run = mn;
#pragma unroll
      for (int t = 0; t < 4; ++t)
#pragma unroll
        for (int r = 0; r < 4; ++r) {
          p[t][r] = __expf(v[t][r] - mn);
          rsum += p[t][r];
        }
      rsum += __shfl_xor(rsum, 16, 64);
      rsum += __shfl_xor(rsum, 32, 64);
      l_run = l_run * corr + rsum;
#pragma unroll
      for (int f = 0; f < 4; ++f) o[f] *= corr;
    }

    // ---- P -> wave-private LDS (packed u32 pairs), no barrier needed
    uint32_t* prow = &P_lds[w][lrow][0];
#pragma unroll
    for (int t = 0; t < 4; ++t)
#pragma unroll
      for (int c = 0; c < 2; ++c) {
        union { bf16_t hh[2]; uint32_t u; } pk;
        pk.hh[0] = (bf16_t)p[t][2 * c];
        pk.hh[1] = (bf16_t)p[t][2 * c + 1];
        prow[8 * t + 2 * lkg + c] = pk.u;
      }
    asm volatile("" ::: "memory");   // compiler-order fence; same-wave LDS is in-order
    const bf16_t* prd = reinterpret_cast<const bf16_t*>(&P_lds[w][lrow][0]);
    bf16x8 pa0 = *reinterpret_cast<const bf16x8*>(prd + lkg * 8);
    bf16x8 pa1 = *reinterpret_cast<const bf16x8*>(prd + 32 + lkg * 8);

    // ---- PV: o[f][r] = O[q=lane&15][d = f*16 + 4lkg + r]
#pragma unroll
    for (int f = 0; f < 4; ++f) {
      o[f] = __builtin_amdgcn_mfma_f32_16x16x32_bf16(vf0[f], pa0, o[f], 0, 0, 0);
      o[f] = __builtin_amdgcn_mfma_f32_16x16x32_bf16(vf1[f], pa1, o[f], 0, 0, 0);
    }
  }

  float inv = 1.0f / l_run;
#pragma unroll
  for (int f = 0; f < 4; ++f) {
    union { bf16_t hh[4]; uint2 u; } ov;
#pragma unroll
    for (int r = 0; r < 4; ++r) ov.hh[r] = (bf16_t)(o[f][r] * inv);
    bf16_t* op = AO + (size_t)(b * NN + qrow) * ND + h * DHEAD + f * 16 + lkg * 4;
    *reinterpret_cast<uint2*>(op) = ov.u;
  }
}

extern "C" void kernel_launch(void* const* d_in, const int* in_sizes, int n_in,
                              void* d_out, int out_size, void* d_ws, size_t ws_size,
                              hipStream_t stream) {
  const float* x  = (const float*)d_in[0];
  const float* Wq = (const float*)d_in[1];
  const float* bq = (const float*)d_in[2];
  const float* Wk = (const float*)d_in[3];
  const float* bk = (const float*)d_in[4];
  const float* Wv = (const float*)d_in[5];
  const float* bv = (const float*)d_in[6];
  const float* Wo = (const float*)d_in[7];
  const float* bo = (const float*)d_in[8];
  float* out = (float*)d_out;

  bf16_t* ws  = (bf16_t*)d_ws;
  bf16_t* xb  = ws;
  bf16_t* Wqb = xb  + 4194304;
  bf16_t* Wkb = Wqb + 1048576;
  bf16_t* Wvb = Wkb + 1048576;
  bf16_t* Wob = Wvb + 1048576;
  bf16_t* Qb  = Wob + 1048576;
  bf16_t* Kb  = Qb  + 4194304;
  bf16_t* VTb = Kb  + 4194304;
  bf16_t* AOb = VTb + 4194304;

  cast_kernel<<<4096, 256, 0, stream>>>(x, xb, 1048576);
  cast4_kernel<<<dim3(1024, 4), 256, 0, stream>>>(Wq, Wk, Wv, Wo, Wqb, Wkb, Wvb, Wob, 262144);

  qkv_gemm<<<dim3(8, 32, 3), 256, 0, stream>>>(xb, Wqb, Wkb, Wvb, bq, bk, bv, Qb, Kb, VTb);
  attn_kernel<<<1024, 256, 0, stream>>>(Qb, Kb, VTb, AOb);
  out_gemm<<<dim3(8, 32), 256, 0, stream>>>(AOb, Wob, bo, out);
}

// Round 3
// 96.202 us; speedup vs baseline: 1.2847x; 1.2847x over previous
//
#include <hip/hip_runtime.h>
#include <hip/hip_bf16.h>
#include <stdint.h>

typedef __bf16 bf16_t;
typedef __bf16 bf16x8 __attribute__((ext_vector_type(8)));
typedef float f32x4 __attribute__((ext_vector_type(4)));

#define NB 2
#define NN 2048
#define ND 1024
#define NH 16
#define DHEAD 64
#define WIN 128

__device__ __forceinline__ void load_lds16(const void* g, void* l) {
  __builtin_amdgcn_global_load_lds(
      (const __attribute__((address_space(1))) uint32_t*)g,
      (__attribute__((address_space(3))) uint32_t*)l, 16, 0, 0);
}

__global__ __launch_bounds__(256) void cast_kernel(const float* __restrict__ in,
                                                   bf16_t* __restrict__ out, int n4) {
  int i = blockIdx.x * 256 + threadIdx.x;
  if (i < n4) {
    float4 v = reinterpret_cast<const float4*>(in)[i];
    union { bf16_t h[4]; uint2 u; } o;
    o.h[0] = (bf16_t)v.x; o.h[1] = (bf16_t)v.y;
    o.h[2] = (bf16_t)v.z; o.h[3] = (bf16_t)v.w;
    reinterpret_cast<uint2*>(out)[i] = o.u;
  }
}

__global__ __launch_bounds__(256) void cast4_kernel(const float* __restrict__ i0, const float* __restrict__ i1,
                                                    const float* __restrict__ i2, const float* __restrict__ i3,
                                                    bf16_t* o0, bf16_t* o1, bf16_t* o2, bf16_t* o3, int n4) {
  int z = blockIdx.y;
  const float* in = (z == 0) ? i0 : (z == 1) ? i1 : (z == 2) ? i2 : i3;
  bf16_t* out = (z == 0) ? o0 : (z == 1) ? o1 : (z == 2) ? o2 : o3;
  int i = blockIdx.x * 256 + threadIdx.x;
  if (i < n4) {
    float4 v = reinterpret_cast<const float4*>(in)[i];
    union { bf16_t h[4]; uint2 u; } o;
    o.h[0] = (bf16_t)v.x; o.h[1] = (bf16_t)v.y;
    o.h[2] = (bf16_t)v.z; o.h[3] = (bf16_t)v.w;
    reinterpret_cast<uint2*>(out)[i] = o.u;
  }
}

// C[m][n] = sum_k A[m][k] * Bw[n][k], K=1024. 128x128 tile, BK=32, 4 waves 2x2.
__device__ __forceinline__ void gemm_tile(const bf16_t* __restrict__ A,
                                          const bf16_t* __restrict__ Bw,
                                          bf16_t* As, bf16_t* Bs,
                                          int m0, int n0, f32x4 acc[4][4]) {
  const int tid  = threadIdx.x;
  const int lane = tid & 63;
  const int wid  = tid >> 6;
  const int wr = wid >> 1, wc = wid & 1;
  const int lrow = lane & 15, lkg = lane >> 4;
  const int srow = lane >> 2, scol = (lane & 3) * 8;

  for (int k0 = 0; k0 < 1024; k0 += 32) {
#pragma unroll
    for (int i = 0; i < 2; ++i) {
      const int rbase = (wid * 2 + i) * 16;
      load_lds16(A  + (size_t)(m0 + rbase + srow) * 1024 + k0 + scol, As + rbase * 32);
      load_lds16(Bw + (size_t)(n0 + rbase + srow) * 1024 + k0 + scol, Bs + rbase * 32);
    }
    __syncthreads();
    bf16x8 af[4], bf[4];
#pragma unroll
    for (int m = 0; m < 4; ++m)
      af[m] = *reinterpret_cast<const bf16x8*>(As + (wr * 64 + m * 16 + lrow) * 32 + lkg * 8);
#pragma unroll
    for (int n = 0; n < 4; ++n)
      bf[n] = *reinterpret_cast<const bf16x8*>(Bs + (wc * 64 + n * 16 + lrow) * 32 + lkg * 8);
#pragma unroll
    for (int m = 0; m < 4; ++m)
#pragma unroll
      for (int n = 0; n < 4; ++n)
        acc[m][n] = __builtin_amdgcn_mfma_f32_16x16x32_bf16(af[m], bf[n], acc[m][n], 0, 0, 0);
    __syncthreads();
  }
}

// z=0: Qh[b][h][tok][64], z=1: Kh same, z=2: VTt[b][h][tile][d][64]
__global__ __launch_bounds__(256, 2)
void qkv_gemm(const bf16_t* __restrict__ xb,
              const bf16_t* __restrict__ Wqb, const bf16_t* __restrict__ Wkb,
              const bf16_t* __restrict__ Wvb,
              const float* __restrict__ bq, const float* __restrict__ bk,
              const float* __restrict__ bv,
              bf16_t* __restrict__ Qh, bf16_t* __restrict__ Kh,
              bf16_t* __restrict__ VTt) {
  __shared__ __align__(16) bf16_t As[128 * 32];
  __shared__ __align__(16) bf16_t Bs[128 * 32];
  const int z = blockIdx.z;
  const bf16_t* Bw  = (z == 0) ? Wqb : (z == 1) ? Wkb : Wvb;
  const float* bias = (z == 0) ? bq  : (z == 1) ? bk  : bv;
  const int m0 = blockIdx.y * 128, n0 = blockIdx.x * 128;
  f32x4 acc[4][4] = {};
  gemm_tile(xb, Bw, As, Bs, m0, n0, acc);

  const int lane = threadIdx.x & 63;
  const int wid  = threadIdx.x >> 6;
  const int wr = wid >> 1, wc = wid & 1;
  const int lrow = lane & 15, lkg = lane >> 4;
#pragma unroll
  for (int m = 0; m < 4; ++m)
#pragma unroll
    for (int n = 0; n < 4; ++n)
#pragma unroll
      for (int r = 0; r < 4; ++r) {
        int row = m0 + wr * 64 + m * 16 + lkg * 4 + r;   // token index (global)
        int col = n0 + wc * 64 + n * 16 + lrow;          // feature index
        float val = acc[m][n][r] + bias[col];
        int bb = row >> 11, tok = row & 2047;
        int hh = col >> 6,  dd = col & 63;
        if (z == 2) {
          VTt[((((size_t)(bb * NH + hh) * 32 + (tok >> 6)) * 64 + dd) << 6) + (tok & 63)] = (bf16_t)val;
        } else {
          bf16_t* outp = (z == 0) ? Qh : Kh;
          outp[(((size_t)(bb * NH + hh) * NN + tok) << 6) + dd] = (bf16_t)val;
        }
      }
}

__global__ __launch_bounds__(256, 2)
void out_gemm(const bf16_t* __restrict__ AOb, const bf16_t* __restrict__ Wob,
              const float* __restrict__ bo, float* __restrict__ Cout) {
  __shared__ __align__(16) bf16_t As[128 * 32];
  __shared__ __align__(16) bf16_t Bs[128 * 32];
  const int m0 = blockIdx.y * 128, n0 = blockIdx.x * 128;
  f32x4 acc[4][4] = {};
  gemm_tile(AOb, Wob, As, Bs, m0, n0, acc);

  const int lane = threadIdx.x & 63;
  const int wid  = threadIdx.x >> 6;
  const int wr = wid >> 1, wc = wid & 1;
  const int lrow = lane & 15, lkg = lane >> 4;
#pragma unroll
  for (int m = 0; m < 4; ++m)
#pragma unroll
    for (int n = 0; n < 4; ++n)
#pragma unroll
      for (int r = 0; r < 4; ++r) {
        int row = m0 + wr * 64 + m * 16 + lkg * 4 + r;
        int col = n0 + wc * 64 + n * 16 + lrow;
        Cout[(size_t)row * 1024 + col] = acc[m][n][r] + bo[col];
      }
}

// ---------------------------------------------------------------------------
// Block-cooperative flash attention, swapped QK^T.
// K/V tiles (64 keys) staged to LDS via global_load_lds (coalesced, swizzled
// source / linear dest), double-buffered, 1 barrier per chunk. 4 waves share
// the staged tiles; each wave owns 16 q-rows; softmax lane-local (q=lane&15).
// LDS = 32KB KV + 8KB P = 40KB -> 4 blocks/CU.
// ---------------------------------------------------------------------------
__global__ __launch_bounds__(256)
void attn_kernel(const bf16_t* __restrict__ Qh, const bf16_t* __restrict__ Kh,
                 const bf16_t* __restrict__ VTt, bf16_t* __restrict__ AO) {
  __shared__ __align__(16) bf16_t KV_lds[2][2][4096];  // [buf][0=K,1=V][64 rows][64]
  __shared__ uint32_t P_lds[4][16][32];                // swizzled 16B chunks, no pad

  const int work = ((blockIdx.x & 7) << 7) | (blockIdx.x >> 3);  // XCD-bijective
  const int qt = work & 31, h = (work >> 5) & 15, b = work >> 9;
  const int tid = threadIdx.x, lane = tid & 63, w = tid >> 6;
  const int lrow = lane & 15, lkg = lane >> 4;
  const int q0 = qt * 64;
  const int qb = q0 + w * 16;
  const int qrow = qb + lrow;
  const int rs7 = lrow & 7;

  // staging: per-lane swizzled global source, linear LDS dest
  const int srow8 = lane >> 3;                    // row within 8-row group
  const int sswz  = 8 * ((lane & 7) ^ srow8);     // element offset (16B-chunk XOR)

  const bf16_t* kbase = Kh  + ((size_t)(b * NH + h) * NN) * DHEAD;
  const bf16_t* vbase = VTt + ((size_t)(b * NH + h) * (NN / 64)) * DHEAD * 64;

  const bf16_t* qptr = Qh + (((size_t)(b * NH + h) * NN + qrow) << 6) + lkg * 8;
  bf16x8 qf0 = *reinterpret_cast<const bf16x8*>(qptr);
  bf16x8 qf1 = *reinterpret_cast<const bf16x8*>(qptr + 32);

  float m_run = -1e30f, l_run = 0.f;
  f32x4 o[4] = {};

  const int kstart = (q0 - WIN > 0) ? (q0 - WIN) : 0;
  const int kend = (q0 + 64 + WIN < NN) ? (q0 + 64 + WIN) : NN;
  const int nch = (kend - kstart) >> 6;
  const float scale = 0.125f;

  auto stage = [&](int bufi, int kc) {
#pragma unroll
    for (int j = 0; j < 2; ++j) {
      const int i = w * 2 + j;                 // 0..7, wave-uniform
      load_lds16(kbase + (((size_t)(kc + i * 8 + srow8)) << 6) + sswz,
                 &KV_lds[bufi][0][i * 512]);
      load_lds16(vbase + (((size_t)((kc >> 6) * 64 + i * 8 + srow8)) << 6) + sswz,
                 &KV_lds[bufi][1][i * 512]);
    }
  };

  stage(0, kstart);
  __syncthreads();   // drains vmcnt(0)

  for (int ic = 0; ic < nch; ++ic) {
    const int kc = kstart + ic * 64;
    const int bi = ic & 1;
    if (ic + 1 < nch) stage(bi ^ 1, kc + 64);

    const bf16_t* Kt = &KV_lds[bi][0][0];
    const bf16_t* Vt = &KV_lds[bi][1][0];

    // QK^T (swapped): s[t][r] = S[k = kc+16t+4lkg+r][q = lane&15]
    f32x4 s[4];
#pragma unroll
    for (int t = 0; t < 4; ++t) {
      const bf16_t* kr = Kt + (t * 16 + lrow) * 64;
      bf16x8 kf0 = *reinterpret_cast<const bf16x8*>(kr + ((lkg ^ rs7) << 3));
      bf16x8 kf1 = *reinterpret_cast<const bf16x8*>(kr + (((4 + lkg) ^ rs7) << 3));
      f32x4 zz = {};
      zz = __builtin_amdgcn_mfma_f32_16x16x32_bf16(kf0, qf0, zz, 0, 0, 0);
      zz = __builtin_amdgcn_mfma_f32_16x16x32_bf16(kf1, qf1, zz, 0, 0, 0);
      s[t] = zz;
    }

    // V fragments (LDS, issued early so lgkm latency hides under softmax)
    bf16x8 vf0[4], vf1[4];
#pragma unroll
    for (int f = 0; f < 4; ++f) {
      const bf16_t* vr = Vt + (f * 16 + lrow) * 64;
      vf0[f] = *reinterpret_cast<const bf16x8*>(vr + ((lkg ^ rs7) << 3));
      vf1[f] = *reinterpret_cast<const bf16x8*>(vr + (((4 + lkg) ^ rs7) << 3));
    }

    // softmax (lane-local q-row)
    const bool needs_mask = (kc < qb - 113) || (kc > qb + 65);  // wave-uniform
    float p[4][4];
    float mloc = -1e30f, rsum = 0.f;
    if (needs_mask) {
      float v[4][4];
#pragma unroll
      for (int t = 0; t < 4; ++t)
#pragma unroll
        for (int r = 0; r < 4; ++r) {
          int k = kc + t * 16 + lkg * 4 + r;
          int d = qrow - k;
          bool ok = (unsigned)(d + WIN) <= 2u * WIN;
          v[t][r] = ok ? s[t][r] * scale : -1e30f;
          mloc = fmaxf(mloc, v[t][r]);
        }
      mloc = fmaxf(mloc, __shfl_xor(mloc, 16, 64));
      mloc = fmaxf(mloc, __shfl_xor(mloc, 32, 64));
      float mn = fmaxf(m_run, mloc);
      float corr = __expf(m_run - mn);
      m_run = mn;
#pragma unroll
      for (int t = 0; t < 4; ++t)
#pragma unroll
        for (int r = 0; r < 4; ++r) {
          int k = kc + t * 16 + lkg * 4 + r;
          int d = qrow - k;
          bool ok = (unsigned)(d + WIN) <= 2u * WIN;
          p[t][r] = ok ? __expf(v[t][r] - mn) : 0.f;
          rsum += p[t][r];
        }
      rsum += __shfl_xor(rsum, 16, 64);
      rsum += __shfl_xor(rsum, 32, 64);
      l_run = l_run * corr + rsum;
#pragma unroll
      for (int f = 0; f < 4; ++f) o[f] *= corr;
    } else {
      float v[4][4];
#pragma unroll
      for (int t = 0; t < 4; ++t)
#pragma unroll
        for (int r = 0; r < 4; ++r) {
          v[t][r] = s[t][r] * scale;
          mloc = fmaxf(mloc, v[t][r]);
        }
      mloc = fmaxf(mloc, __shfl_xor(mloc, 16, 64));
      mloc = fmaxf(mloc, __shfl_xor(mloc, 32, 64));
      float mn = fmaxf(m_run, mloc);
      float corr = __expf(m_run - mn);
      m_run = mn;
#pragma unroll
      for (int t = 0; t < 4; ++t)
#pragma unroll
        for (int r = 0; r < 4; ++r) {
          p[t][r] = __expf(v[t][r] - mn);
          rsum += p[t][r];
        }
      rsum += __shfl_xor(rsum, 16, 64);
      rsum += __shfl_xor(rsum, 32, 64);
      l_run = l_run * corr + rsum;
#pragma unroll
      for (int f = 0; f < 4; ++f) o[f] *= corr;
    }

    // P -> wave-private swizzled LDS (u32 stores, 16B-chunk XOR), no barrier
    uint32_t* prow = &P_lds[w][lrow][0];
#pragma unroll
    for (int t = 0; t < 4; ++t)
#pragma unroll
      for (int c = 0; c < 2; ++c) {
        union { bf16_t hh[2]; uint32_t u; } pk;
        pk.hh[0] = (bf16_t)p[t][2 * c];
        pk.hh[1] = (bf16_t)p[t][2 * c + 1];
        int L = 8 * t + 2 * lkg + c;
        int pos = (((L >> 2) ^ rs7) << 2) | (L & 3);
        prow[pos] = pk.u;
      }
    asm volatile("" ::: "memory");   // same-wave LDS write->read ordering
    const bf16_t* prd = reinterpret_cast<const bf16_t*>(&P_lds[w][lrow][0]);
    bf16x8 pa0 = *reinterpret_cast<const bf16x8*>(prd + ((lkg ^ rs7) << 3));
    bf16x8 pa1 = *reinterpret_cast<const bf16x8*>(prd + (((4 + lkg) ^ rs7) << 3));

    // PV: o[f][r] = O[d = f*16 + 4lkg + r][q = lane&15]
#pragma unroll
    for (int f = 0; f < 4; ++f) {
      o[f] = __builtin_amdgcn_mfma_f32_16x16x32_bf16(vf0[f], pa0, o[f], 0, 0, 0);
      o[f] = __builtin_amdgcn_mfma_f32_16x16x32_bf16(vf1[f], pa1, o[f], 0, 0, 0);
    }
    __syncthreads();   // drains stage vmcnt + protects buffer reuse
  }

  float inv = 1.0f / l_run;
#pragma unroll
  for (int f = 0; f < 4; ++f) {
    union { bf16_t hh[4]; uint2 u; } ov;
#pragma unroll
    for (int r = 0; r < 4; ++r) ov.hh[r] = (bf16_t)(o[f][r] * inv);
    bf16_t* op = AO + (size_t)(b * NN + qrow) * ND + h * DHEAD + f * 16 + lkg * 4;
    *reinterpret_cast<uint2*>(op) = ov.u;
  }
}

extern "C" void kernel_launch(void* const* d_in, const int* in_sizes, int n_in,
                              void* d_out, int out_size, void* d_ws, size_t ws_size,
                              hipStream_t stream) {
  const float* x  = (const float*)d_in[0];
  const float* Wq = (const float*)d_in[1];
  const float* bq = (const float*)d_in[2];
  const float* Wk = (const float*)d_in[3];
  const float* bk = (const float*)d_in[4];
  const float* Wv = (const float*)d_in[5];
  const float* bv = (const float*)d_in[6];
  const float* Wo = (const float*)d_in[7];
  const float* bo = (const float*)d_in[8];
  float* out = (float*)d_out;

  bf16_t* ws  = (bf16_t*)d_ws;
  bf16_t* xb  = ws;
  bf16_t* Wqb = xb  + 4194304;
  bf16_t* Wkb = Wqb + 1048576;
  bf16_t* Wvb = Wkb + 1048576;
  bf16_t* Wob = Wvb + 1048576;
  bf16_t* Qh  = Wob + 1048576;
  bf16_t* Kh  = Qh  + 4194304;
  bf16_t* VTt = Kh  + 4194304;
  bf16_t* AOb = VTt + 4194304;

  cast_kernel<<<4096, 256, 0, stream>>>(x, xb, 1048576);
  cast4_kernel<<<dim3(1024, 4), 256, 0, stream>>>(Wq, Wk, Wv, Wo, Wqb, Wkb, Wvb, Wob, 262144);

  qkv_gemm<<<dim3(8, 32, 3), 256, 0, stream>>>(xb, Wqb, Wkb, Wvb, bq, bk, bv, Qh, Kh, VTt);
  attn_kernel<<<1024, 256, 0, stream>>>(Qh, Kh, VTt, AOb);
  out_gemm<<<dim3(8, 32), 256, 0, stream>>>(AOb, Wob, bo, out);
}